// Round 1
// baseline (187.130 us; speedup 1.0000x reference)
//
#include <hip/hip_runtime.h>

#define EDIM 128
#define MDIM 8
#define ADIM 64
#define NFR  50
#define NCOL (NFR * MDIM)   // 400
#define NSLICE 64           // contention slices for softmax denominator atomics

typedef __attribute__((ext_vector_type(8))) short short8;
typedef __attribute__((ext_vector_type(4))) float f32x4;

__device__ __forceinline__ float waveReduceSum(float v) {
    #pragma unroll
    for (int s = 32; s >= 1; s >>= 1) v += __shfl_xor(v, s, 64);
    return v;
}
__device__ __forceinline__ short f2bf(float x) {
    unsigned u = __float_as_uint(x);
    u += 0x7FFFu + ((u >> 16) & 1u);
    return (short)(u >> 16);
}
__device__ __forceinline__ float bf2f(short s) {
    return __uint_as_float(((unsigned)(unsigned short)s) << 16);
}
// Swizzled A-frag layout. Block (Mt=r>>4, Kt=e>>5) of 512 shorts; within it,
// slot = lane ^ (quad<<1) (bijective -> MFMA-side b128 reads conflict-free;
// writer/reader (f,kgroup) pattern lands 8 distinct words/bank = min cycles).
__device__ __forceinline__ int fragOff(int r, int e) {   // e multiple of 8
    int q = (e >> 3) & 3;
    int slot = (q * 16 + (r & 15)) ^ (q << 1);
    int block = ((r >> 4) << 2) | (e >> 5);
    return (block * 64 + slot) * 8;
}
__device__ __forceinline__ int slotR(int l) { return l ^ (((l >> 4) & 3) << 1); }

// k0: pre-pack WA (B-frags 4Nt x 4Kt) and Key (4Kt, N padded 8->16 with 0);
// also zero the softmax-denominator slices (harness poisons ws each iter).
__global__ __launch_bounds__(256)
void k0_prep(const float* __restrict__ WA, const float* __restrict__ Key,
             short* __restrict__ WAfrag, short* __restrict__ Keyfrag,
             float* __restrict__ Ssum)
{
    int t = blockIdx.x * 256 + threadIdx.x;
    for (int i = t; i < NSLICE * NCOL; i += 5 * 256) Ssum[i] = 0.f;
    if (t < 1024) {
        int lane = t & 63;
        int Kt = (t >> 6) & 3;
        int Nt = t >> 8;
        int n  = Nt * 16 + (lane & 15);
        int k0 = Kt * 32 + (lane >> 4) * 8;
        short8 v;
        #pragma unroll
        for (int j = 0; j < 8; ++j) v[j] = f2bf(WA[(size_t)(k0 + j) * ADIM + n]);
        *(short8*)(WAfrag + (size_t)t * 8) = v;
    } else if (t < 1280) {
        int i = t - 1024;
        int lane = i & 63;
        int Kt = i >> 6;
        int n  = lane & 15;
        int k0 = Kt * 32 + (lane >> 4) * 8;
        short8 v;
        #pragma unroll
        for (int j = 0; j < 8; ++j)
            v[j] = (n < MDIM) ? f2bf(Key[(size_t)(k0 + j) * MDIM + n]) : (short)0;
        *(short8*)(Keyfrag + (size_t)i * 8) = v;
    }
}

// k1: att_key via MFMA. Thread (fl=t>>4, kg=t&15) owns friend fl+16*it, e=kg*8..+7.
// Side outputs: masked fe as bf16 (streamed back in k3 -> kills k3's gather),
// and per-column exp-sum partials (max-free softmax: |att_key| <= ~1.14, exp safe).
__global__ __launch_bounds__(256, 4)
void k1_attkey(const int* __restrict__ input_u, const int* __restrict__ input_uf,
               const float* __restrict__ uidW, const short* __restrict__ Keyfrag,
               float* __restrict__ att_key, short* __restrict__ feW,
               float* __restrict__ Ssum, int user_num)
{
    const int b = blockIdx.x, t = threadIdx.x, w = t >> 6, l = t & 63;
    __shared__ short crossF[64 * EDIM];   // 16 KB
    __shared__ float uidnL[EDIM];
    __shared__ float redW[4];
    __shared__ int ufL[64];

    const int u = input_u[b];
    float x = (t < EDIM) ? uidW[(size_t)u * EDIM + t] : 0.f;
    float s = waveReduceSum(x * x);
    if (l == 0) redW[w] = s;
    if (t < NFR) ufL[t] = input_uf[(size_t)b * NFR + t];
    else if (t < 64) ufL[t] = user_num;
    __syncthreads();
    float uinv = 1.0f / fmaxf(sqrtf(redW[0] + redW[1] + redW[2] + redW[3]), 1e-12f);
    if (t < EDIM) uidnL[t] = x * uinv;
    __syncthreads();

    const int kg = t & 15, fl = t >> 4;
    const int e0 = kg * 8;
    float4 un0 = *(const float4*)&uidnL[e0];
    float4 un1 = *(const float4*)&uidnL[e0 + 4];

    #pragma unroll
    for (int it = 0; it < 4; ++it) {
        int f = fl + 16 * it;
        short8 outv = {0, 0, 0, 0, 0, 0, 0, 0};
        if (f < NFR) {
            int fid = ufL[f];
            float fn = (fid != user_num) ? 1.f : 0.f;
            const float* fp = uidW + (size_t)fid * EDIM + e0;
            float4 g0 = *(const float4*)fp;
            float4 g1 = *(const float4*)(fp + 4);
            g0.x *= fn; g0.y *= fn; g0.z *= fn; g0.w *= fn;
            g1.x *= fn; g1.y *= fn; g1.z *= fn; g1.w *= fn;
            // spill masked fe (bf16) for k3's streaming read
            short8 fev;
            fev[0] = f2bf(g0.x); fev[1] = f2bf(g0.y);
            fev[2] = f2bf(g0.z); fev[3] = f2bf(g0.w);
            fev[4] = f2bf(g1.x); fev[5] = f2bf(g1.y);
            fev[6] = f2bf(g1.z); fev[7] = f2bf(g1.w);
            *(short8*)(feW + ((size_t)b * NFR + f) * EDIM + e0) = fev;
            float fss = g0.x*g0.x + g0.y*g0.y + g0.z*g0.z + g0.w*g0.w
                      + g1.x*g1.x + g1.y*g1.y + g1.z*g1.z + g1.w*g1.w;
            fss += __shfl_xor(fss, 1, 64);
            fss += __shfl_xor(fss, 2, 64);
            fss += __shfl_xor(fss, 4, 64);
            fss += __shfl_xor(fss, 8, 64);
            float inv = 1.0f / fmaxf(sqrtf(fss), 1e-12f);
            outv[0] = f2bf(un0.x * g0.x * inv);
            outv[1] = f2bf(un0.y * g0.y * inv);
            outv[2] = f2bf(un0.z * g0.z * inv);
            outv[3] = f2bf(un0.w * g0.w * inv);
            outv[4] = f2bf(un1.x * g1.x * inv);
            outv[5] = f2bf(un1.y * g1.y * inv);
            outv[6] = f2bf(un1.z * g1.z * inv);
            outv[7] = f2bf(un1.w * g1.w * inv);
        }
        *(short8*)&crossF[fragOff(f, e0)] = outv;
    }
    __syncthreads();

    f32x4 acc = {0.f, 0.f, 0.f, 0.f};
    const int sl = slotR(l);
    #pragma unroll
    for (int Kt = 0; Kt < 4; ++Kt) {
        short8 a  = *(const short8*)&crossF[(((w << 2) | Kt) * 64 + sl) * 8];
        short8 bf = *(const short8*)(Keyfrag + (size_t)((Kt * 64 + l)) * 8);
        acc = __builtin_amdgcn_mfma_f32_16x16x32_bf16(a, bf, acc, 0, 0, 0);
    }
    const int m = l & 15;
    if (m < MDIM) {
        float* Ss = Ssum + (size_t)(b & (NSLICE - 1)) * NCOL;
        const int fbase = w * 16 + (l >> 4) * 4;
        #pragma unroll
        for (int r = 0; r < 4; ++r) {
            int f = fbase + r;
            if (f < NFR) {
                att_key[((size_t)b * NFR + f) * MDIM + m] = acc[r];
                // masked entries have acc==0 -> contribute exp(0)=1, matching
                // reference softmax(axis=0) denominator semantics
                atomicAdd(&Ss[f * MDIM + m], __expf(acc[r]));
            }
        }
    }
}

// k2b: merge NSLICE partials per column -> inv denominator
__global__ __launch_bounds__(256)
void k2b_merge(const float* __restrict__ Ssum, float* __restrict__ ise)
{
    int col = blockIdx.x * 256 + threadIdx.x;
    if (col >= NCOL) return;
    float S = 0.f;
    #pragma unroll
    for (int s = 0; s < NSLICE; ++s) S += Ssum[s * NCOL + col];
    ise[col] = 1.0f / S;
}

// k3: am precompute -> f2 frag (b128) -> MFMA h -> fold -> j -> friend sum -> score
// fe now streamed from feW (coalesced, L3-resident) instead of re-gathered.
__global__ __launch_bounds__(256, 4)
void k3_final(const int* __restrict__ input_u, const int* __restrict__ input_i,
              const int* __restrict__ input_uf, const float* __restrict__ uidW,
              const float* __restrict__ iidW, const float* __restrict__ i_bias,
              const float* __restrict__ Mem, const short* __restrict__ WAfrag,
              const float* __restrict__ BA, const float* __restrict__ U_omega,
              const float* __restrict__ att_key, const short* __restrict__ feW,
              const float* __restrict__ ise, float* __restrict__ out,
              int user_num)
{
    const int b = blockIdx.x, t = threadIdx.x, w = t >> 6, l = t & 63;
    __shared__ short f2F[64 * EDIM];      // 16 KB
    __shared__ float amL[NCOL];
    __shared__ int ufL[64];
    __shared__ float pPart[4 * 64];
    __shared__ float jxL[64];
    __shared__ float accW[4][EDIM];
    __shared__ float red2[2];
    __shared__ float wsS;

    if (t < NFR) ufL[t] = input_uf[(size_t)b * NFR + t];
    else if (t < 64) ufL[t] = user_num;
    __syncthreads();

    for (int i = t; i < NCOL; i += 256) {
        float ak = att_key[(size_t)b * NCOL + i];
        amL[i] = (ufL[i >> 3] != user_num) ? __expf(ak) * ise[i] : 0.f;
    }

    const int kg = t & 15, fl = t >> 4;
    const int e0 = kg * 8;
    float4 mA[MDIM], mB[MDIM];            // Mem slice in regs, reused 4 passes
    #pragma unroll
    for (int m = 0; m < MDIM; ++m) {
        mA[m] = *(const float4*)&Mem[m * EDIM + e0];
        mB[m] = *(const float4*)&Mem[m * EDIM + e0 + 4];
    }
    __syncthreads();

    // phase 1: f2 (bf16) -> swizzled frag, one b128 write per (f, e-octet)
    #pragma unroll
    for (int it = 0; it < 4; ++it) {
        int f = fl + 16 * it;
        short8 outv = {0, 0, 0, 0, 0, 0, 0, 0};
        if (f < NFR) {
            short8 fv = *(const short8*)(feW + ((size_t)b * NFR + f) * EDIM + e0);
            float4 am0 = *(const float4*)&amL[f * 8];
            float4 am1 = *(const float4*)&amL[f * 8 + 4];
            float4 fa = {0.f, 0.f, 0.f, 0.f}, fb = {0.f, 0.f, 0.f, 0.f};
            #pragma unroll
            for (int m = 0; m < 4; ++m) {
                float c0 = (&am0.x)[m], c1 = (&am1.x)[m];
                fa.x += c0 * mA[m].x + c1 * mA[m + 4].x;
                fa.y += c0 * mA[m].y + c1 * mA[m + 4].y;
                fa.z += c0 * mA[m].z + c1 * mA[m + 4].z;
                fa.w += c0 * mA[m].w + c1 * mA[m + 4].w;
                fb.x += c0 * mB[m].x + c1 * mB[m + 4].x;
                fb.y += c0 * mB[m].y + c1 * mB[m + 4].y;
                fb.z += c0 * mB[m].z + c1 * mB[m + 4].z;
                fb.w += c0 * mB[m].w + c1 * mB[m + 4].w;
            }
            outv[0] = f2bf(fa.x * bf2f(fv[0]));
            outv[1] = f2bf(fa.y * bf2f(fv[1]));
            outv[2] = f2bf(fa.z * bf2f(fv[2]));
            outv[3] = f2bf(fa.w * bf2f(fv[3]));
            outv[4] = f2bf(fb.x * bf2f(fv[4]));
            outv[5] = f2bf(fb.y * bf2f(fv[5]));
            outv[6] = f2bf(fb.z * bf2f(fv[6]));
            outv[7] = f2bf(fb.w * bf2f(fv[7]));
        }
        *(short8*)&f2F[fragOff(f, e0)] = outv;
    }
    __syncthreads();

    // phase 2: h = f2 x WA
    const int sl = slotR(l);
    f32x4 acc[4];
    #pragma unroll
    for (int Mt = 0; Mt < 4; ++Mt) acc[Mt] = (f32x4){0.f, 0.f, 0.f, 0.f};
    #pragma unroll
    for (int Kt = 0; Kt < 4; ++Kt) {
        short8 bf = *(const short8*)(WAfrag + (size_t)(((w << 2) | Kt) * 64 + l) * 8);
        #pragma unroll
        for (int Mt = 0; Mt < 4; ++Mt) {
            short8 a = *(const short8*)&f2F[(((Mt << 2) | Kt) * 64 + sl) * 8];
            acc[Mt] = __builtin_amdgcn_mfma_f32_16x16x32_bf16(a, bf, acc[Mt], 0, 0, 0);
        }
    }

    // phase 3: fold relu(h+BA)*U_omega over 16 cols -> per-friend p
    const int aIdx = w * 16 + (l & 15);
    const float ba = BA[aIdx];
    const float uo = U_omega[aIdx];
    float v[16];
    #pragma unroll
    for (int Mt = 0; Mt < 4; ++Mt)
        #pragma unroll
        for (int r = 0; r < 4; ++r)
            v[Mt * 4 + r] = fmaxf(acc[Mt][r] + ba, 0.f) * uo;

    const bool c0 = l & 1, c1 = l & 2, c2 = l & 4, c3 = l & 8;
    #pragma unroll
    for (int k = 0; k < 8; ++k) {
        float lo = v[k], hi = v[k + 8];
        float send = c0 ? lo : hi;
        float recv = __shfl_xor(send, 1, 64);
        v[k] = c0 ? (hi + recv) : (lo + recv);
    }
    #pragma unroll
    for (int k = 0; k < 4; ++k) {
        float lo = v[k], hi = v[k + 4];
        float send = c1 ? lo : hi;
        float recv = __shfl_xor(send, 2, 64);
        v[k] = c1 ? (hi + recv) : (lo + recv);
    }
    #pragma unroll
    for (int k = 0; k < 2; ++k) {
        float lo = v[k], hi = v[k + 2];
        float send = c2 ? lo : hi;
        float recv = __shfl_xor(send, 4, 64);
        v[k] = c2 ? (hi + recv) : (lo + recv);
    }
    {
        float lo = v[0], hi = v[1];
        float send = c3 ? lo : hi;
        float recv = __shfl_xor(send, 8, 64);
        v[0] = c3 ? (hi + recv) : (lo + recv);
    }
    const int vIdx = ((l & 1) << 3) | ((l & 2) << 1) | ((l & 4) >> 1) | ((l & 8) >> 3);
    const int fLane = (vIdx >> 2) * 16 + (l >> 4) * 4 + (vIdx & 3);
    pPart[w * 64 + fLane] = v[0];
    __syncthreads();

    if (t < 64) {
        float p = pPart[t] + pPart[64 + t] + pPart[128 + t] + pPart[192 + t];
        float jv = 0.f;
        if (t < NFR && ufL[t] != user_num) jv = __expf(p);
        jxL[t] = jv;
        float wsum = waveReduceSum(jv);
        if (t == 0) wsS = wsum + 1e-8f;
    }
    __syncthreads();

    // phase 4: acc[e-octet] = sum_f j[f]*f2[f][e]; b128 reads (pad rows are zero)
    float pa[8] = {0.f, 0.f, 0.f, 0.f, 0.f, 0.f, 0.f, 0.f};
    #pragma unroll
    for (int it = 0; it < 4; ++it) {
        int f = fl + 16 * it;             // f<64; jxL=0 & f2F=0 for pads
        float jf = jxL[f];
        short8 vv = *(const short8*)&f2F[fragOff(f, e0)];
        #pragma unroll
        for (int j = 0; j < 8; ++j) pa[j] += jf * bf2f(vv[j]);
    }
    #pragma unroll
    for (int j = 0; j < 8; ++j) {
        pa[j] += __shfl_xor(pa[j], 16, 64);
        pa[j] += __shfl_xor(pa[j], 32, 64);
    }
    if (l < 16) {
        #pragma unroll
        for (int j = 0; j < 8; ++j) accW[w][l * 8 + j] = pa[j];
    }
    __syncthreads();

    if (t < EDIM) {
        const float winv = 1.0f / wsS;
        float fr = (accW[0][t] + accW[1][t] + accW[2][t] + accW[3][t]) * winv;
        const int u = input_u[b];
        const int ii = input_i[b];
        float sc = (uidW[(size_t)u * EDIM + t] + fr) * iidW[(size_t)ii * EDIM + t];
        float p = waveReduceSum(sc);
        if ((t & 63) == 0) red2[t >> 6] = p;
    }
    __syncthreads();
    if (t == 0) out[b] = red2[0] + red2[1] + i_bias[input_i[b]];
}

extern "C" void kernel_launch(void* const* d_in, const int* in_sizes, int n_in,
                              void* d_out, int out_size, void* d_ws, size_t ws_size,
                              hipStream_t stream)
{
    const int*   input_u  = (const int*)d_in[0];
    const int*   input_i  = (const int*)d_in[1];
    const int*   input_uf = (const int*)d_in[2];
    const float* uidW     = (const float*)d_in[3];
    const float* iidW     = (const float*)d_in[4];
    const float* i_bias   = (const float*)d_in[5];
    const float* Key      = (const float*)d_in[6];
    const float* Mem      = (const float*)d_in[7];
    const float* WA       = (const float*)d_in[8];
    const float* BA       = (const float*)d_in[9];
    const float* U_om     = (const float*)d_in[10];

    const int B = in_sizes[0];
    const int user_num = in_sizes[3] / EDIM - 1;

    float* att  = (float*)d_ws;                                  // B*400
    float* Ssum = att + (size_t)B * NCOL;                        // 64*400
    float* ise  = Ssum + NSLICE * NCOL;                          // 400
    short* WAfrag  = (short*)(ise + NCOL);                       // 8192
    short* Keyfrag = WAfrag + 4 * 4 * 64 * 8;                    // 2048
    short* feW     = Keyfrag + 4 * 64 * 8;                       // B*50*128 bf16

    k0_prep<<<5, 256, 0, stream>>>(WA, Key, WAfrag, Keyfrag, Ssum);
    k1_attkey<<<B, 256, 0, stream>>>(input_u, input_uf, uidW, Keyfrag, att, feW,
                                     Ssum, user_num);
    k2b_merge<<<2, 256, 0, stream>>>(Ssum, ise);
    k3_final<<<B, 256, 0, stream>>>(input_u, input_i, input_uf, uidW, iidW, i_bias,
                                    Mem, WAfrag, BA, U_om, att, feW, ise,
                                    (float*)d_out, user_num);
}

// Round 2
// 172.967 us; speedup vs baseline: 1.0819x; 1.0819x over previous
//
#include <hip/hip_runtime.h>

#define EDIM 128
#define MDIM 8
#define ADIM 64
#define NFR  50
#define NCOL (NFR * MDIM)   // 400
#define NSLICE 64           // contention slices for softmax denominator atomics

typedef __attribute__((ext_vector_type(8))) short short8;
typedef __attribute__((ext_vector_type(4))) float f32x4;

__device__ __forceinline__ float waveReduceSum(float v) {
    #pragma unroll
    for (int s = 32; s >= 1; s >>= 1) v += __shfl_xor(v, s, 64);
    return v;
}
__device__ __forceinline__ short f2bf(float x) {
    unsigned u = __float_as_uint(x);
    u += 0x7FFFu + ((u >> 16) & 1u);
    return (short)(u >> 16);
}
__device__ __forceinline__ float bf2f(short s) {
    return __uint_as_float(((unsigned)(unsigned short)s) << 16);
}
// Swizzled A-frag layout (proven in prior rounds). Block (Mt=r>>4, Kt=e>>5) of
// 512 shorts; within it slot = (q*16+(r&15)) ^ (q<<1), q=(e>>3)&3.
__device__ __forceinline__ int fragOff(int r, int e) {   // e multiple of 8
    int q = (e >> 3) & 3;
    int slot = (q * 16 + (r & 15)) ^ (q << 1);
    int block = ((r >> 4) << 2) | (e >> 5);
    return (block * 64 + slot) * 8;
}
__device__ __forceinline__ int slotR(int l) { return l ^ (((l >> 4) & 3) << 1); }

// k0: pre-pack WA (B-frags 4Nt x 4Kt) and Key (4Kt, N padded 8->16 with 0);
// also zero the softmax-denominator slices (harness poisons ws each iter).
__global__ __launch_bounds__(256)
void k0_prep(const float* __restrict__ WA, const float* __restrict__ Key,
             short* __restrict__ WAfrag, short* __restrict__ Keyfrag,
             float* __restrict__ Ssum)
{
    int t = blockIdx.x * 256 + threadIdx.x;
    for (int i = t; i < NSLICE * NCOL; i += 5 * 256) Ssum[i] = 0.f;
    if (t < 1024) {
        int lane = t & 63;
        int Kt = (t >> 6) & 3;
        int Nt = t >> 8;
        int n  = Nt * 16 + (lane & 15);
        int k0 = Kt * 32 + (lane >> 4) * 8;
        short8 v;
        #pragma unroll
        for (int j = 0; j < 8; ++j) v[j] = f2bf(WA[(size_t)(k0 + j) * ADIM + n]);
        *(short8*)(WAfrag + (size_t)t * 8) = v;
    } else if (t < 1280) {
        int i = t - 1024;
        int lane = i & 63;
        int Kt = i >> 6;
        int n  = lane & 15;
        int k0 = Kt * 32 + (lane >> 4) * 8;
        short8 v;
        #pragma unroll
        for (int j = 0; j < 8; ++j)
            v[j] = (n < MDIM) ? f2bf(Key[(size_t)(k0 + j) * MDIM + n]) : (short)0;
        *(short8*)(Keyfrag + (size_t)i * 8) = v;
    }
}

// k1: wave-per-b, barrier-free. Each wave: gather 50 friend rows, normalize,
// cross -> swizzled frag (own 16KB LDS slice), 16 MFMAs -> att_key + atomic
// exp-sum partials (max-free softmax: |att_key| <= ~1.14).
__global__ __launch_bounds__(256, 2)
void k1_attkey(const int* __restrict__ input_u, const int* __restrict__ input_uf,
               const float* __restrict__ uidW, const short* __restrict__ Keyfrag,
               float* __restrict__ att_key, float* __restrict__ Ssum,
               int user_num, int B)
{
    __shared__ short crossF4[4][64 * EDIM];   // 64 KB
    __shared__ float uidn4[4][EDIM];          // 2 KB
    const int w = threadIdx.x >> 6, l = threadIdx.x & 63;
    const int b = blockIdx.x * 4 + w;
    if (b >= B) return;
    short* cF = crossF4[w];
    float* uidn = uidn4[w];

    const int u = input_u[b];
    int ufv = (l < NFR) ? input_uf[(size_t)b * NFR + l] : user_num;
    float x0 = uidW[(size_t)u * EDIM + l];
    float x1 = uidW[(size_t)u * EDIM + 64 + l];
    float s = waveReduceSum(x0 * x0 + x1 * x1);
    float uinv = 1.0f / fmaxf(sqrtf(s), 1e-12f);
    uidn[l] = x0 * uinv;
    uidn[64 + l] = x1 * uinv;
    __builtin_amdgcn_wave_barrier();

    const int kg = l & 15, fl = l >> 4;
    const int e0 = kg * 8;
    float4 un0 = *(const float4*)&uidn[e0];
    float4 un1 = *(const float4*)&uidn[e0 + 4];

    #pragma unroll 4
    for (int it = 0; it < 13; ++it) {       // f = fl + 4*it covers 0..51
        int f = fl + 4 * it;
        short8 outv = {0, 0, 0, 0, 0, 0, 0, 0};
        if (f < NFR) {
            int fid = __shfl(ufv, f, 64);
            float fn = (fid != user_num) ? 1.f : 0.f;
            const float* fp = uidW + (size_t)fid * EDIM + e0;
            float4 g0 = *(const float4*)fp;
            float4 g1 = *(const float4*)(fp + 4);
            g0.x *= fn; g0.y *= fn; g0.z *= fn; g0.w *= fn;
            g1.x *= fn; g1.y *= fn; g1.z *= fn; g1.w *= fn;
            float fss = g0.x*g0.x + g0.y*g0.y + g0.z*g0.z + g0.w*g0.w
                      + g1.x*g1.x + g1.y*g1.y + g1.z*g1.z + g1.w*g1.w;
            fss += __shfl_xor(fss, 1, 64);
            fss += __shfl_xor(fss, 2, 64);
            fss += __shfl_xor(fss, 4, 64);
            fss += __shfl_xor(fss, 8, 64);
            float inv = 1.0f / fmaxf(sqrtf(fss), 1e-12f);
            outv[0] = f2bf(un0.x * g0.x * inv);
            outv[1] = f2bf(un0.y * g0.y * inv);
            outv[2] = f2bf(un0.z * g0.z * inv);
            outv[3] = f2bf(un0.w * g0.w * inv);
            outv[4] = f2bf(un1.x * g1.x * inv);
            outv[5] = f2bf(un1.y * g1.y * inv);
            outv[6] = f2bf(un1.z * g1.z * inv);
            outv[7] = f2bf(un1.w * g1.w * inv);
        }
        *(short8*)&cF[fragOff(f, e0)] = outv;
    }
    __builtin_amdgcn_wave_barrier();

    const int sl = slotR(l);
    f32x4 acc[4];
    #pragma unroll
    for (int Mt = 0; Mt < 4; ++Mt) acc[Mt] = (f32x4){0.f, 0.f, 0.f, 0.f};
    #pragma unroll
    for (int Kt = 0; Kt < 4; ++Kt) {
        short8 bf = *(const short8*)(Keyfrag + (size_t)(Kt * 64 + l) * 8);
        #pragma unroll
        for (int Mt = 0; Mt < 4; ++Mt) {
            short8 a = *(const short8*)&cF[(((Mt << 2) | Kt) * 64 + sl) * 8];
            acc[Mt] = __builtin_amdgcn_mfma_f32_16x16x32_bf16(a, bf, acc[Mt], 0, 0, 0);
        }
    }
    const int m = l & 15;
    if (m < MDIM) {
        float* Ss = Ssum + (size_t)(b & (NSLICE - 1)) * NCOL;
        #pragma unroll
        for (int Mt = 0; Mt < 4; ++Mt) {
            const int fbase = Mt * 16 + (l >> 4) * 4;
            #pragma unroll
            for (int r = 0; r < 4; ++r) {
                int f = fbase + r;
                if (f < NFR) {
                    att_key[((size_t)b * NFR + f) * MDIM + m] = acc[Mt][r];
                    // masked rows have acc==0 -> exp(0)=1, matching reference
                    // softmax(axis=0) denominator semantics
                    atomicAdd(&Ss[f * MDIM + m], __expf(acc[Mt][r]));
                }
            }
        }
    }
}

// k2b: merge NSLICE partials per column -> inv denominator
__global__ __launch_bounds__(256)
void k2b_merge(const float* __restrict__ Ssum, float* __restrict__ ise)
{
    int col = blockIdx.x * 256 + threadIdx.x;
    if (col >= NCOL) return;
    float S = 0.f;
    #pragma unroll
    for (int s = 0; s < NSLICE; ++s) S += Ssum[s * NCOL + col];
    ise[col] = 1.0f / S;
}

// k3: wave-per-b, barrier-free. am -> f2 frag -> 64 MFMAs -> fold -> j ->
// friend sum -> score. All reductions in-wave (shuffles); LDS slices per-wave.
__global__ __launch_bounds__(256, 2)
void k3_final(const int* __restrict__ input_u, const int* __restrict__ input_i,
              const int* __restrict__ input_uf, const float* __restrict__ uidW,
              const float* __restrict__ iidW, const float* __restrict__ i_bias,
              const float* __restrict__ Mem, const short* __restrict__ WAfrag,
              const float* __restrict__ BA, const float* __restrict__ U_omega,
              const float* __restrict__ att_key, const float* __restrict__ ise,
              float* __restrict__ out, int user_num, int B)
{
    __shared__ short f2F4[4][64 * EDIM];   // 64 KB
    __shared__ float amL4[4][NCOL];        // 6.25 KB
    __shared__ float jxL4[4][64];          // 1 KB
    const int w = threadIdx.x >> 6, l = threadIdx.x & 63;
    const int b = blockIdx.x * 4 + w;
    if (b >= B) return;
    short* f2F = f2F4[w];
    float* amL = amL4[w];
    float* jxL = jxL4[w];

    const int u = input_u[b];
    const int ii = input_i[b];
    const float ib = i_bias[ii];
    int ufv = (l < NFR) ? input_uf[(size_t)b * NFR + l] : user_num;

    const int kg = l & 15, fl = l >> 4;
    const int e0 = kg * 8;

    // am = fn * exp(att_key) * ise  (max-free)
    #pragma unroll
    for (int c = 0; c < 7; ++c) {
        int i = l + 64 * c;
        if (i < NCOL) {
            float ak = att_key[(size_t)b * NCOL + i];
            int fid = __shfl(ufv, i >> 3, 64);
            amL[i] = (fid != user_num) ? __expf(ak) * ise[i] : 0.f;
        }
    }

    float4 mA[MDIM], mB[MDIM];            // Mem slice for this lane's e-octet
    #pragma unroll
    for (int m = 0; m < MDIM; ++m) {
        mA[m] = *(const float4*)&Mem[m * EDIM + e0];
        mB[m] = *(const float4*)&Mem[m * EDIM + e0 + 4];
    }
    __builtin_amdgcn_wave_barrier();

    // phase 1: f2 = (am x Mem) * fe -> swizzled frag (all 64 rows written)
    #pragma unroll 4
    for (int it = 0; it < 16; ++it) {
        int f = fl + 4 * it;
        short8 outv = {0, 0, 0, 0, 0, 0, 0, 0};
        if (f < NFR) {
            int fid = __shfl(ufv, f, 64);
            const float* fp = uidW + (size_t)fid * EDIM + e0;
            float4 g0 = *(const float4*)fp;
            float4 g1 = *(const float4*)(fp + 4);
            float4 am0 = *(const float4*)&amL[f * 8];
            float4 am1 = *(const float4*)&amL[f * 8 + 4];
            float4 fa = {0.f, 0.f, 0.f, 0.f}, fb = {0.f, 0.f, 0.f, 0.f};
            #pragma unroll
            for (int m = 0; m < 4; ++m) {
                float c0 = (&am0.x)[m], c1 = (&am1.x)[m];
                fa.x += c0 * mA[m].x + c1 * mA[m + 4].x;
                fa.y += c0 * mA[m].y + c1 * mA[m + 4].y;
                fa.z += c0 * mA[m].z + c1 * mA[m + 4].z;
                fa.w += c0 * mA[m].w + c1 * mA[m + 4].w;
                fb.x += c0 * mB[m].x + c1 * mB[m + 4].x;
                fb.y += c0 * mB[m].y + c1 * mB[m + 4].y;
                fb.z += c0 * mB[m].z + c1 * mB[m + 4].z;
                fb.w += c0 * mB[m].w + c1 * mB[m + 4].w;
            }
            // masked friends: am==0 -> fa=fb=0 -> f2=0 (matches reference)
            outv[0] = f2bf(fa.x * g0.x);
            outv[1] = f2bf(fa.y * g0.y);
            outv[2] = f2bf(fa.z * g0.z);
            outv[3] = f2bf(fa.w * g0.w);
            outv[4] = f2bf(fb.x * g1.x);
            outv[5] = f2bf(fb.y * g1.y);
            outv[6] = f2bf(fb.z * g1.z);
            outv[7] = f2bf(fb.w * g1.w);
        }
        *(short8*)&f2F[fragOff(f, e0)] = outv;
    }
    __builtin_amdgcn_wave_barrier();

    // phase 2: h = f2(64x128) x WA(128x64), 64 MFMAs per wave
    const int sl = slotR(l);
    f32x4 acc[4][4];
    #pragma unroll
    for (int Mt = 0; Mt < 4; ++Mt)
        #pragma unroll
        for (int Nt = 0; Nt < 4; ++Nt) acc[Mt][Nt] = (f32x4){0.f, 0.f, 0.f, 0.f};
    #pragma unroll
    for (int Kt = 0; Kt < 4; ++Kt) {
        short8 a[4];
        #pragma unroll
        for (int Mt = 0; Mt < 4; ++Mt)
            a[Mt] = *(const short8*)&f2F[(((Mt << 2) | Kt) * 64 + sl) * 8];
        #pragma unroll
        for (int Nt = 0; Nt < 4; ++Nt) {
            short8 bf = *(const short8*)(WAfrag + (size_t)(((Nt << 2) | Kt) * 64 + l) * 8);
            #pragma unroll
            for (int Mt = 0; Mt < 4; ++Mt)
                acc[Mt][Nt] = __builtin_amdgcn_mfma_f32_16x16x32_bf16(a[Mt], bf, acc[Mt][Nt], 0, 0, 0);
        }
    }

    // phase 3: fold relu(h+BA)*U_omega over all 64 cols -> per-friend p
    float ba4[4], uo4[4];
    #pragma unroll
    for (int Nt = 0; Nt < 4; ++Nt) {
        ba4[Nt] = BA[Nt * 16 + kg];
        uo4[Nt] = U_omega[Nt * 16 + kg];
    }
    float v[16];
    #pragma unroll
    for (int Mt = 0; Mt < 4; ++Mt)
        #pragma unroll
        for (int r = 0; r < 4; ++r) {
            float sv = 0.f;
            #pragma unroll
            for (int Nt = 0; Nt < 4; ++Nt)
                sv += fmaxf(acc[Mt][Nt][r] + ba4[Nt], 0.f) * uo4[Nt];
            v[Mt * 4 + r] = sv;
        }

    const bool c0 = l & 1, c1 = l & 2, c2 = l & 4, c3 = l & 8;
    #pragma unroll
    for (int k = 0; k < 8; ++k) {
        float lo = v[k], hi = v[k + 8];
        float send = c0 ? lo : hi;
        float recv = __shfl_xor(send, 1, 64);
        v[k] = c0 ? (hi + recv) : (lo + recv);
    }
    #pragma unroll
    for (int k = 0; k < 4; ++k) {
        float lo = v[k], hi = v[k + 4];
        float send = c1 ? lo : hi;
        float recv = __shfl_xor(send, 2, 64);
        v[k] = c1 ? (hi + recv) : (lo + recv);
    }
    #pragma unroll
    for (int k = 0; k < 2; ++k) {
        float lo = v[k], hi = v[k + 2];
        float send = c2 ? lo : hi;
        float recv = __shfl_xor(send, 4, 64);
        v[k] = c2 ? (hi + recv) : (lo + recv);
    }
    {
        float lo = v[0], hi = v[1];
        float send = c3 ? lo : hi;
        float recv = __shfl_xor(send, 8, 64);
        v[0] = c3 ? (hi + recv) : (lo + recv);
    }
    const int vIdx = ((l & 1) << 3) | ((l & 2) << 1) | ((l & 4) >> 1) | ((l & 8) >> 3);
    const int fLane = (vIdx >> 2) * 16 + (l >> 4) * 4 + (vIdx & 3);

    int ufF = __shfl(ufv, fLane, 64);
    float jv = 0.f;
    if (fLane < NFR && ufF != user_num) jv = __expf(v[0]);
    jxL[fLane] = jv;
    float winv = 1.0f / (waveReduceSum(jv) + 1e-8f);
    __builtin_amdgcn_wave_barrier();

    // phase 4: friend-weighted sum of f2 (pad rows are zero, jx pad = 0)
    float pa[8] = {0.f, 0.f, 0.f, 0.f, 0.f, 0.f, 0.f, 0.f};
    #pragma unroll 4
    for (int it = 0; it < 16; ++it) {
        int f = fl + 4 * it;
        float jf = jxL[f];
        short8 vv = *(const short8*)&f2F[fragOff(f, e0)];
        #pragma unroll
        for (int j = 0; j < 8; ++j) pa[j] += jf * bf2f(vv[j]);
    }
    #pragma unroll
    for (int j = 0; j < 8; ++j) {
        pa[j] += __shfl_xor(pa[j], 16, 64);
        pa[j] += __shfl_xor(pa[j], 32, 64);
    }

    // epilogue: score = sum_e (uid+friend)*iid + i_bias (4x duplicated -> *0.25)
    const float* up = uidW + (size_t)u * EDIM + e0;
    const float* ip = iidW + (size_t)ii * EDIM + e0;
    float4 u0 = *(const float4*)up;
    float4 u1 = *(const float4*)(up + 4);
    float4 i0 = *(const float4*)ip;
    float4 i1 = *(const float4*)(ip + 4);
    float sc = 0.f;
    #pragma unroll
    for (int j = 0; j < 4; ++j) {
        sc += ((&u0.x)[j] + pa[j] * winv) * (&i0.x)[j];
        sc += ((&u1.x)[j] + pa[j + 4] * winv) * (&i1.x)[j];
    }
    float red = waveReduceSum(sc);
    if (l == 0) out[b] = red * 0.25f + ib;
}

extern "C" void kernel_launch(void* const* d_in, const int* in_sizes, int n_in,
                              void* d_out, int out_size, void* d_ws, size_t ws_size,
                              hipStream_t stream)
{
    const int*   input_u  = (const int*)d_in[0];
    const int*   input_i  = (const int*)d_in[1];
    const int*   input_uf = (const int*)d_in[2];
    const float* uidW     = (const float*)d_in[3];
    const float* iidW     = (const float*)d_in[4];
    const float* i_bias   = (const float*)d_in[5];
    const float* Key      = (const float*)d_in[6];
    const float* Mem      = (const float*)d_in[7];
    const float* WA       = (const float*)d_in[8];
    const float* BA       = (const float*)d_in[9];
    const float* U_om     = (const float*)d_in[10];

    const int B = in_sizes[0];
    const int user_num = in_sizes[3] / EDIM - 1;

    float* att  = (float*)d_ws;                                  // B*400
    float* Ssum = att + (size_t)B * NCOL;                        // 64*400
    float* ise  = Ssum + NSLICE * NCOL;                          // 400
    short* WAfrag  = (short*)(ise + NCOL);                       // 8192
    short* Keyfrag = WAfrag + 4 * 4 * 64 * 8;                    // 2048

    const int nb = (B + 3) / 4;
    k0_prep<<<5, 256, 0, stream>>>(WA, Key, WAfrag, Keyfrag, Ssum);
    k1_attkey<<<nb, 256, 0, stream>>>(input_u, input_uf, uidW, Keyfrag, att,
                                      Ssum, user_num, B);
    k2b_merge<<<2, 256, 0, stream>>>(Ssum, ise);
    k3_final<<<nb, 256, 0, stream>>>(input_u, input_i, input_uf, uidW, iidW, i_bias,
                                     Mem, WAfrag, BA, U_om, att, ise,
                                     (float*)d_out, user_num, B);
}